// Round 2
// baseline (1512.130 us; speedup 1.0000x reference)
//
#include <hip/hip_runtime.h>
#include <hip/hip_bf16.h>

#define EPSBN 1e-5f

static __host__ __device__ inline size_t alignup(size_t x) { return (x + 255) & ~(size_t)255; }

// ---------------- CSR build ----------------

__global__ __launch_bounds__(256) void k_count(const int* __restrict__ dst, int* __restrict__ cnt, int E, int N) {
    int i = blockIdx.x * blockDim.x + threadIdx.x;
    int base = i * 4;
    if (base + 3 < E) {
        int4 d = *reinterpret_cast<const int4*>(dst + base);
        if ((unsigned)d.x < (unsigned)N) atomicAdd(&cnt[d.x], 1);
        if ((unsigned)d.y < (unsigned)N) atomicAdd(&cnt[d.y], 1);
        if ((unsigned)d.z < (unsigned)N) atomicAdd(&cnt[d.z], 1);
        if ((unsigned)d.w < (unsigned)N) atomicAdd(&cnt[d.w], 1);
    } else {
        for (int k = base; k < E; ++k) {
            int d = dst[k];
            if ((unsigned)d < (unsigned)N) atomicAdd(&cnt[d], 1);
        }
    }
}

__global__ __launch_bounds__(256) void k_dinv(const int* __restrict__ cnt, float* __restrict__ dinv, int N) {
    int v = blockIdx.x * blockDim.x + threadIdx.x;
    if (v < N) dinv[v] = rsqrtf((float)(cnt[v] + 1));   // +1 self-loop; always >=1
}

__global__ __launch_bounds__(256) void k_scan_a(const int* __restrict__ cnt, int* __restrict__ partials, int N) {
    __shared__ int lds[256];
    int i0 = blockIdx.x * 1024 + threadIdx.x * 4;
    int s = 0;
#pragma unroll
    for (int k = 0; k < 4; ++k) if (i0 + k < N) s += cnt[i0 + k];
    lds[threadIdx.x] = s;
    __syncthreads();
    for (int off = 128; off >= 1; off >>= 1) {
        if ((int)threadIdx.x < off) lds[threadIdx.x] += lds[threadIdx.x + off];
        __syncthreads();
    }
    if (threadIdx.x == 0) partials[blockIdx.x] = lds[0];
}

__global__ void k_scan_b(int* __restrict__ partials, int* __restrict__ row_off, int NB, int N) {
    if (threadIdx.x == 0 && blockIdx.x == 0) {
        int run = 0;
        for (int i = 0; i < NB; ++i) { int t = partials[i]; partials[i] = run; run += t; }
        row_off[N] = run;
    }
}

__global__ __launch_bounds__(256) void k_scan_c(const int* __restrict__ cnt, const int* __restrict__ partials,
                                                int* __restrict__ row_off, int* __restrict__ cursor, int N) {
    __shared__ int lds[256];
    int b = blockIdx.x;
    int base = partials[b];
    int i0 = b * 1024 + threadIdx.x * 4;
    int v[4];
#pragma unroll
    for (int k = 0; k < 4; ++k) v[k] = (i0 + k < N) ? cnt[i0 + k] : 0;
    int tsum = v[0] + v[1] + v[2] + v[3];
    lds[threadIdx.x] = tsum;
    __syncthreads();
    for (int off = 1; off < 256; off <<= 1) {
        int t = ((int)threadIdx.x >= off) ? lds[threadIdx.x - off] : 0;
        __syncthreads();
        lds[threadIdx.x] += t;
        __syncthreads();
    }
    int run = lds[threadIdx.x] - tsum + base;   // exclusive prefix
#pragma unroll
    for (int k = 0; k < 4; ++k) {
        if (i0 + k < N) { row_off[i0 + k] = run; cursor[i0 + k] = run; run += v[k]; }
    }
}

__global__ __launch_bounds__(256) void k_fill(const int* __restrict__ src, const int* __restrict__ dst,
                                              int* __restrict__ cursor, int* __restrict__ csr, int E, int N) {
    int i = blockIdx.x * blockDim.x + threadIdx.x;
    int base = i * 4;
    if (base + 3 < E) {
        int4 s4 = *reinterpret_cast<const int4*>(src + base);
        int4 d4 = *reinterpret_cast<const int4*>(dst + base);
        int p;
        if ((unsigned)d4.x < (unsigned)N) { p = atomicAdd(&cursor[d4.x], 1); if (p < E) csr[p] = s4.x; }
        if ((unsigned)d4.y < (unsigned)N) { p = atomicAdd(&cursor[d4.y], 1); if (p < E) csr[p] = s4.y; }
        if ((unsigned)d4.z < (unsigned)N) { p = atomicAdd(&cursor[d4.z], 1); if (p < E) csr[p] = s4.z; }
        if ((unsigned)d4.w < (unsigned)N) { p = atomicAdd(&cursor[d4.w], 1); if (p < E) csr[p] = s4.w; }
    } else {
        for (int k = base; k < E; ++k) {
            int d = dst[k];
            if ((unsigned)d < (unsigned)N) {
                int p = atomicAdd(&cursor[d], 1);
                if (p < E) csr[p] = src[k];
            }
        }
    }
}

// ---------------- Layer 1: aggregate 5-dim x, matmul 5->32 in epilogue, BN1 stats ----------------

__global__ __launch_bounds__(256) void k_agg1(const float* __restrict__ x, const int* __restrict__ csr,
                                              const int* __restrict__ row_off, const float* __restrict__ dinv,
                                              const float* __restrict__ W1, const float* __restrict__ b1,
                                              float* __restrict__ out, float* __restrict__ sum, float* __restrict__ sq,
                                              int N) {
    __shared__ float lss[256], lsq[256];
    int lane = threadIdx.x & 63;
    int wave = (blockIdx.x * blockDim.x + threadIdx.x) >> 6;
    int nw = (gridDim.x * blockDim.x) >> 6;
    int c = lane & 31;
    float w0 = W1[c], w1 = W1[32 + c], w2 = W1[64 + c], w3 = W1[96 + c], w4 = W1[128 + c];
    float bc = b1[c];
    float ls = 0.f, lq = 0.f;
    for (int v = wave; v < N; v += nw) {
        int s0 = row_off[v], s1 = row_off[v + 1];
        float a0 = 0, a1 = 0, a2 = 0, a3 = 0, a4 = 0;
        for (int e = s0 + lane; e < s1; e += 64) {
            int s = csr[e];
            float w = dinv[s];
            const float* xp = x + (size_t)s * 5;
            a0 = fmaf(w, xp[0], a0);
            a1 = fmaf(w, xp[1], a1);
            a2 = fmaf(w, xp[2], a2);
            a3 = fmaf(w, xp[3], a3);
            a4 = fmaf(w, xp[4], a4);
        }
#pragma unroll
        for (int off = 32; off >= 1; off >>= 1) {
            a0 += __shfl_xor(a0, off);
            a1 += __shfl_xor(a1, off);
            a2 += __shfl_xor(a2, off);
            a3 += __shfl_xor(a3, off);
            a4 += __shfl_xor(a4, off);
        }
        if (lane < 32) {
            float dv = dinv[v];
            float dv2 = dv * dv;
            const float* xv = x + (size_t)v * 5;
            float t0 = dv * a0 + dv2 * xv[0];
            float t1 = dv * a1 + dv2 * xv[1];
            float t2 = dv * a2 + dv2 * xv[2];
            float t3 = dv * a3 + dv2 * xv[3];
            float t4 = dv * a4 + dv2 * xv[4];
            float h = bc;
            h = fmaf(t0, w0, h); h = fmaf(t1, w1, h); h = fmaf(t2, w2, h);
            h = fmaf(t3, w3, h); h = fmaf(t4, w4, h);
            out[(size_t)v * 32 + c] = h;
            ls += h; lq += h * h;
        }
    }
    lss[threadIdx.x] = ls; lsq[threadIdx.x] = lq;
    __syncthreads();
    if (threadIdx.x < 32) {
        float s = 0.f, q = 0.f;
#pragma unroll
        for (int j = 0; j < 8; ++j) { s += lss[threadIdx.x + 32 * j]; q += lsq[threadIdx.x + 32 * j]; }
        atomicAdd(&sum[threadIdx.x], s);
        atomicAdd(&sq[threadIdx.x], q);
    }
}

// ---------------- BN params: a = gamma*rsqrt(var+eps), d = beta - mean*a ----------------

__global__ void k_bnparam(const float* __restrict__ sum, const float* __restrict__ sq,
                          const float* __restrict__ gamma, const float* __restrict__ beta,
                          float* __restrict__ aOut, float* __restrict__ dOut, float invN) {
    int c = threadIdx.x;
    if (c < 32) {
        float mean = sum[c] * invN;
        float var = fmaxf(sq[c] * invN - mean * mean, 0.f);
        float rinv = rsqrtf(var + EPSBN);
        float a = gamma[c] * rinv;
        aOut[c] = a;
        dOut[c] = beta[c] - mean * a;
    }
}

// ---------------- h2 = relu(bn1(out1)) @ W2, in place ----------------

__global__ __launch_bounds__(256) void k_h2(float* __restrict__ buf, const float* __restrict__ W2,
                                            const float* __restrict__ a1, const float* __restrict__ d1, int N) {
    __shared__ float W2s[1024];
    __shared__ float rbuf[8][33];
    for (int i = threadIdx.x; i < 1024; i += 256) W2s[i] = W2[i];
    int g = threadIdx.x >> 5, c = threadIdx.x & 31;
    int v = blockIdx.x * 8 + g;
    float r = 0.f;
    if (v < N) {
        float val = buf[(size_t)v * 32 + c];
        r = fmaxf(fmaf(a1[c], val, d1[c]), 0.f);
    }
    __syncthreads();
    rbuf[g][c] = r;
    __syncthreads();
    if (v < N) {
        float h = 0.f;
#pragma unroll
        for (int k = 0; k < 32; ++k) h = fmaf(rbuf[g][k], W2s[k * 32 + c], h);
        buf[(size_t)v * 32 + c] = h;
    }
}

// ---------------- Layer 2: gather h2 rows, BN2 stats ----------------

__global__ __launch_bounds__(256) void k_agg2(const float* __restrict__ h2, const int* __restrict__ csr,
                                              const int* __restrict__ row_off, const float* __restrict__ dinv,
                                              const float* __restrict__ b2, float* __restrict__ out,
                                              float* __restrict__ sum, float* __restrict__ sq, int N) {
    __shared__ float lss[256], lsq[256];
    int lane = threadIdx.x & 63;
    int wave = (blockIdx.x * blockDim.x + threadIdx.x) >> 6;
    int nw = (gridDim.x * blockDim.x) >> 6;
    int c = lane & 31;
    int half = lane >> 5;
    float bc = b2[c];
    float ls = 0.f, lq = 0.f;
    for (int v = wave; v < N; v += nw) {
        int s0 = row_off[v], s1 = row_off[v + 1];
        float acc = 0.f;
        for (int e = s0 + half; e < s1; e += 2) {
            int s = csr[e];
            acc = fmaf(dinv[s], h2[(size_t)s * 32 + c], acc);
        }
        acc += __shfl_xor(acc, 32);
        if (lane < 32) {
            float dv = dinv[v];
            float hv = h2[(size_t)v * 32 + c];
            float o = bc + dv * acc + dv * dv * hv;
            out[(size_t)v * 32 + c] = o;
            ls += o; lq += o * o;
        }
    }
    lss[threadIdx.x] = ls; lsq[threadIdx.x] = lq;
    __syncthreads();
    if (threadIdx.x < 32) {
        float s = 0.f, q = 0.f;
#pragma unroll
        for (int j = 0; j < 8; ++j) { s += lss[threadIdx.x + 32 * j]; q += lsq[threadIdx.x + 32 * j]; }
        atomicAdd(&sum[threadIdx.x], s);
        atomicAdd(&sq[threadIdx.x], q);
    }
}

// ---------------- p[v] = dinv[v] * (relu(bn2(out2[v])) @ W3) ----------------

__global__ __launch_bounds__(256) void k_h3p(const float* __restrict__ buf, const float* __restrict__ a2,
                                             const float* __restrict__ d2, const float* __restrict__ W3,
                                             const float* __restrict__ dinv, float* __restrict__ p, int N) {
    int c = threadIdx.x & 31;
    int v = blockIdx.x * 8 + (threadIdx.x >> 5);
    if (v >= N) return;
    float val = buf[(size_t)v * 32 + c];
    float r = fmaxf(fmaf(a2[c], val, d2[c]), 0.f) * W3[c];
#pragma unroll
    for (int off = 16; off >= 1; off >>= 1) r += __shfl_xor(r, off, 32);
    if (c == 0) p[v] = dinv[v] * r;
}

// ---------------- Layer 3: scalar gather-reduce ----------------

__global__ __launch_bounds__(256) void k_agg3(const float* __restrict__ p, const int* __restrict__ csr,
                                              const int* __restrict__ row_off, const float* __restrict__ dinv,
                                              const float* __restrict__ b3, float* __restrict__ out, int N) {
    int lane = threadIdx.x & 63;
    int wave = (blockIdx.x * blockDim.x + threadIdx.x) >> 6;
    int nw = (gridDim.x * blockDim.x) >> 6;
    for (int v = wave; v < N; v += nw) {
        int s0 = row_off[v], s1 = row_off[v + 1];
        float acc = 0.f;
        for (int e = s0 + lane; e < s1; e += 64) acc += p[csr[e]];
#pragma unroll
        for (int off = 32; off >= 1; off >>= 1) acc += __shfl_xor(acc, off);
        if (lane == 0) out[v] = b3[0] + dinv[v] * acc + dinv[v] * p[v];
    }
}

// ---------------- launch ----------------

extern "C" void kernel_launch(void* const* d_in, const int* in_sizes, int n_in,
                              void* d_out, int out_size, void* d_ws, size_t ws_size,
                              hipStream_t stream) {
    const float* x      = (const float*)d_in[0];
    const int*   ei     = (const int*)d_in[1];
    const float* W1     = (const float*)d_in[2];
    const float* b1     = (const float*)d_in[3];
    const float* gamma1 = (const float*)d_in[4];
    const float* beta1  = (const float*)d_in[5];
    const float* W2     = (const float*)d_in[6];
    const float* b2     = (const float*)d_in[7];
    const float* gamma2 = (const float*)d_in[8];
    const float* beta2  = (const float*)d_in[9];
    const float* W3     = (const float*)d_in[10];
    const float* b3     = (const float*)d_in[11];

    int N = out_size;             // 100000 nodes
    int E = in_sizes[1] / 2;      // 6400000 edges
    const int* srcp = ei;
    const int* dstp = ei + E;

    char* w = (char*)d_ws;
    int*   csr     = (int*)w;          w += alignup((size_t)E * 4);
    int*   cnt     = (int*)w;          w += alignup((size_t)N * 4);
    int*   row_off = (int*)w;          w += alignup((size_t)(N + 1) * 4);
    int*   cursor  = (int*)w;          w += alignup((size_t)N * 4);
    float* dinv    = (float*)w;        w += alignup((size_t)N * 4);
    float* buf1    = (float*)w;        w += alignup((size_t)N * 32 * 4);
    float* buf2    = (float*)w;        w += alignup((size_t)N * 32 * 4);
    float* pbuf    = (float*)w;        w += alignup((size_t)N * 4);
    float* stats   = (float*)w;        w += alignup(256 * 4);   // sum1,sq1,sum2,sq2 then a1,d1,a2,d2
    int*   partials= (int*)w;          w += alignup(1024 * 4);

    float* sum1 = stats, *sq1 = stats + 32, *sum2 = stats + 64, *sq2 = stats + 96;
    float* a1 = stats + 128, *d1 = stats + 160, *a2 = stats + 192, *d2 = stats + 224;

    hipMemsetAsync(cnt, 0, (size_t)N * 4, stream);
    hipMemsetAsync(stats, 0, 128 * 4, stream);

    int eb = (E + 1023) / 1024;
    int NB = (N + 1023) / 1024;

    k_count<<<eb, 256, 0, stream>>>(dstp, cnt, E, N);
    k_dinv<<<(N + 255) / 256, 256, 0, stream>>>(cnt, dinv, N);
    k_scan_a<<<NB, 256, 0, stream>>>(cnt, partials, N);
    k_scan_b<<<1, 64, 0, stream>>>(partials, row_off, NB, N);
    k_scan_c<<<NB, 256, 0, stream>>>(cnt, partials, row_off, cursor, N);
    k_fill<<<eb, 256, 0, stream>>>(srcp, dstp, cursor, csr, E, N);

    float invN = 1.0f / (float)N;

    k_agg1<<<1024, 256, 0, stream>>>(x, csr, row_off, dinv, W1, b1, buf1, sum1, sq1, N);
    k_bnparam<<<1, 32, 0, stream>>>(sum1, sq1, gamma1, beta1, a1, d1, invN);
    k_h2<<<(N + 7) / 8, 256, 0, stream>>>(buf1, W2, a1, d1, N);
    k_agg2<<<1024, 256, 0, stream>>>(buf1, csr, row_off, dinv, b2, buf2, sum2, sq2, N);
    k_bnparam<<<1, 32, 0, stream>>>(sum2, sq2, gamma2, beta2, a2, d2, invN);
    k_h3p<<<(N + 7) / 8, 256, 0, stream>>>(buf2, a2, d2, W3, dinv, pbuf, N);
    k_agg3<<<1024, 256, 0, stream>>>(pbuf, csr, row_off, dinv, b3, (float*)d_out, N);
}

// Round 3
// 1258.097 us; speedup vs baseline: 1.2019x; 1.2019x over previous
//
#include <hip/hip_runtime.h>
#include <hip/hip_bf16.h>

#define EPSBN 1e-5f
#define NPART 8

static __host__ __device__ inline size_t alignup(size_t x) { return (x + 255) & ~(size_t)255; }

// ---------------- CSR build (dst-range partitioned for XCD/L2 locality) ----------------
// blocks with blockIdx.x % 8 == p handle only dst in [p*rsz, p*rsz+rsz).
// Round-robin block->XCD dispatch makes each XCD's atomics + csr writes land in a
// private ~3.2MB slice that fits its 4MB L2 -> full-line writebacks, no cross-XCD bounce.

__global__ __launch_bounds__(256) void k_count_p(const int* __restrict__ dst, int* __restrict__ cnt, int E, int N) {
    int part = blockIdx.x & (NPART - 1);
    int rsz = (N + NPART - 1) / NPART;
    int lo = part * rsz;
    int hi = min(N, lo + rsz);
    int bpart = blockIdx.x >> 3;
    int nb = gridDim.x >> 3;
    int tid = bpart * blockDim.x + threadIdx.x;
    int nthr = nb * blockDim.x;
    int ngroups = E >> 2;
    for (int g = tid; g < ngroups; g += nthr) {
        int4 d = *reinterpret_cast<const int4*>(dst + (size_t)g * 4);
        if (d.x >= lo && d.x < hi) atomicAdd(&cnt[d.x], 1);
        if (d.y >= lo && d.y < hi) atomicAdd(&cnt[d.y], 1);
        if (d.z >= lo && d.z < hi) atomicAdd(&cnt[d.z], 1);
        if (d.w >= lo && d.w < hi) atomicAdd(&cnt[d.w], 1);
    }
    if (tid == 0) {
        for (int k = ngroups * 4; k < E; ++k) {
            int d = dst[k];
            if (d >= lo && d < hi) atomicAdd(&cnt[d], 1);
        }
    }
}

__global__ __launch_bounds__(256) void k_fill_p(const int* __restrict__ src, const int* __restrict__ dst,
                                                int* __restrict__ cursor, int* __restrict__ csr, int E, int N) {
    int part = blockIdx.x & (NPART - 1);
    int rsz = (N + NPART - 1) / NPART;
    int lo = part * rsz;
    int hi = min(N, lo + rsz);
    int bpart = blockIdx.x >> 3;
    int nb = gridDim.x >> 3;
    int tid = bpart * blockDim.x + threadIdx.x;
    int nthr = nb * blockDim.x;
    int ngroups = E >> 2;
    for (int g = tid; g < ngroups; g += nthr) {
        int4 d = *reinterpret_cast<const int4*>(dst + (size_t)g * 4);
        bool bx = (d.x >= lo && d.x < hi);
        bool by = (d.y >= lo && d.y < hi);
        bool bz = (d.z >= lo && d.z < hi);
        bool bw = (d.w >= lo && d.w < hi);
        if (bx || by || bz || bw) {
            int4 s = *reinterpret_cast<const int4*>(src + (size_t)g * 4);
            int p;
            if (bx) { p = atomicAdd(&cursor[d.x], 1); if (p < E) csr[p] = s.x; }
            if (by) { p = atomicAdd(&cursor[d.y], 1); if (p < E) csr[p] = s.y; }
            if (bz) { p = atomicAdd(&cursor[d.z], 1); if (p < E) csr[p] = s.z; }
            if (bw) { p = atomicAdd(&cursor[d.w], 1); if (p < E) csr[p] = s.w; }
        }
    }
    if (tid == 0) {
        for (int k = ngroups * 4; k < E; ++k) {
            int d = dst[k];
            if (d >= lo && d < hi) {
                int p = atomicAdd(&cursor[d], 1);
                if (p < E) csr[p] = src[k];
            }
        }
    }
}

__global__ __launch_bounds__(256) void k_dinv(const int* __restrict__ cnt, float* __restrict__ dinv, int N) {
    int v = blockIdx.x * blockDim.x + threadIdx.x;
    if (v < N) dinv[v] = rsqrtf((float)(cnt[v] + 1));   // +1 self-loop; always >=1
}

__global__ __launch_bounds__(256) void k_scan_a(const int* __restrict__ cnt, int* __restrict__ partials, int N) {
    __shared__ int lds[256];
    int i0 = blockIdx.x * 1024 + threadIdx.x * 4;
    int s = 0;
#pragma unroll
    for (int k = 0; k < 4; ++k) if (i0 + k < N) s += cnt[i0 + k];
    lds[threadIdx.x] = s;
    __syncthreads();
    for (int off = 128; off >= 1; off >>= 1) {
        if ((int)threadIdx.x < off) lds[threadIdx.x] += lds[threadIdx.x + off];
        __syncthreads();
    }
    if (threadIdx.x == 0) partials[blockIdx.x] = lds[0];
}

__global__ void k_scan_b(int* __restrict__ partials, int* __restrict__ row_off, int NB, int N) {
    if (threadIdx.x == 0 && blockIdx.x == 0) {
        int run = 0;
        for (int i = 0; i < NB; ++i) { int t = partials[i]; partials[i] = run; run += t; }
        row_off[N] = run;
    }
}

__global__ __launch_bounds__(256) void k_scan_c(const int* __restrict__ cnt, const int* __restrict__ partials,
                                                int* __restrict__ row_off, int* __restrict__ cursor, int N) {
    __shared__ int lds[256];
    int b = blockIdx.x;
    int base = partials[b];
    int i0 = b * 1024 + threadIdx.x * 4;
    int v[4];
#pragma unroll
    for (int k = 0; k < 4; ++k) v[k] = (i0 + k < N) ? cnt[i0 + k] : 0;
    int tsum = v[0] + v[1] + v[2] + v[3];
    lds[threadIdx.x] = tsum;
    __syncthreads();
    for (int off = 1; off < 256; off <<= 1) {
        int t = ((int)threadIdx.x >= off) ? lds[threadIdx.x - off] : 0;
        __syncthreads();
        lds[threadIdx.x] += t;
        __syncthreads();
    }
    int run = lds[threadIdx.x] - tsum + base;   // exclusive prefix
#pragma unroll
    for (int k = 0; k < 4; ++k) {
        if (i0 + k < N) { row_off[i0 + k] = run; cursor[i0 + k] = run; run += v[k]; }
    }
}

// ---------------- Layer 1: aggregate 5-dim x, matmul 5->32 in epilogue, BN1 stats ----------------

__global__ __launch_bounds__(256) void k_agg1(const float* __restrict__ x, const int* __restrict__ csr,
                                              const int* __restrict__ row_off, const float* __restrict__ dinv,
                                              const float* __restrict__ W1, const float* __restrict__ b1,
                                              float* __restrict__ out, float* __restrict__ sum, float* __restrict__ sq,
                                              int N) {
    __shared__ float lss[256], lsq[256];
    int lane = threadIdx.x & 63;
    int wave = (blockIdx.x * blockDim.x + threadIdx.x) >> 6;
    int nw = (gridDim.x * blockDim.x) >> 6;
    int c = lane & 31;
    float w0 = W1[c], w1 = W1[32 + c], w2 = W1[64 + c], w3 = W1[96 + c], w4 = W1[128 + c];
    float bc = b1[c];
    float ls = 0.f, lq = 0.f;
    for (int v = wave; v < N; v += nw) {
        int s0 = row_off[v], s1 = row_off[v + 1];
        float a0 = 0, a1 = 0, a2 = 0, a3 = 0, a4 = 0;
        for (int e = s0 + lane; e < s1; e += 64) {
            int s = csr[e];
            float w = dinv[s];
            const float* xp = x + (size_t)s * 5;
            a0 = fmaf(w, xp[0], a0);
            a1 = fmaf(w, xp[1], a1);
            a2 = fmaf(w, xp[2], a2);
            a3 = fmaf(w, xp[3], a3);
            a4 = fmaf(w, xp[4], a4);
        }
#pragma unroll
        for (int off = 32; off >= 1; off >>= 1) {
            a0 += __shfl_xor(a0, off);
            a1 += __shfl_xor(a1, off);
            a2 += __shfl_xor(a2, off);
            a3 += __shfl_xor(a3, off);
            a4 += __shfl_xor(a4, off);
        }
        if (lane < 32) {
            float dv = dinv[v];
            float dv2 = dv * dv;
            const float* xv = x + (size_t)v * 5;
            float t0 = dv * a0 + dv2 * xv[0];
            float t1 = dv * a1 + dv2 * xv[1];
            float t2 = dv * a2 + dv2 * xv[2];
            float t3 = dv * a3 + dv2 * xv[3];
            float t4 = dv * a4 + dv2 * xv[4];
            float h = bc;
            h = fmaf(t0, w0, h); h = fmaf(t1, w1, h); h = fmaf(t2, w2, h);
            h = fmaf(t3, w3, h); h = fmaf(t4, w4, h);
            out[(size_t)v * 32 + c] = h;
            ls += h; lq += h * h;
        }
    }
    lss[threadIdx.x] = ls; lsq[threadIdx.x] = lq;
    __syncthreads();
    if (threadIdx.x < 32) {
        float s = 0.f, q = 0.f;
#pragma unroll
        for (int j = 0; j < 8; ++j) { s += lss[threadIdx.x + 32 * j]; q += lsq[threadIdx.x + 32 * j]; }
        atomicAdd(&sum[threadIdx.x], s);
        atomicAdd(&sq[threadIdx.x], q);
    }
}

// ---------------- BN params: a = gamma*rsqrt(var+eps), d = beta - mean*a ----------------

__global__ void k_bnparam(const float* __restrict__ sum, const float* __restrict__ sq,
                          const float* __restrict__ gamma, const float* __restrict__ beta,
                          float* __restrict__ aOut, float* __restrict__ dOut, float invN) {
    int c = threadIdx.x;
    if (c < 32) {
        float mean = sum[c] * invN;
        float var = fmaxf(sq[c] * invN - mean * mean, 0.f);
        float rinv = rsqrtf(var + EPSBN);
        float a = gamma[c] * rinv;
        aOut[c] = a;
        dOut[c] = beta[c] - mean * a;
    }
}

// ---------------- h2 = relu(bn1(out1)) @ W2, in place ----------------

__global__ __launch_bounds__(256) void k_h2(float* __restrict__ buf, const float* __restrict__ W2,
                                            const float* __restrict__ a1, const float* __restrict__ d1, int N) {
    __shared__ float W2s[1024];
    __shared__ float rbuf[8][33];
    for (int i = threadIdx.x; i < 1024; i += 256) W2s[i] = W2[i];
    int g = threadIdx.x >> 5, c = threadIdx.x & 31;
    int v = blockIdx.x * 8 + g;
    float r = 0.f;
    if (v < N) {
        float val = buf[(size_t)v * 32 + c];
        r = fmaxf(fmaf(a1[c], val, d1[c]), 0.f);
    }
    __syncthreads();
    rbuf[g][c] = r;
    __syncthreads();
    if (v < N) {
        float h = 0.f;
#pragma unroll
        for (int k = 0; k < 32; ++k) h = fmaf(rbuf[g][k], W2s[k * 32 + c], h);
        buf[(size_t)v * 32 + c] = h;
    }
}

// ---------------- Layer 2: gather h2 rows, BN2 stats ----------------

__global__ __launch_bounds__(256) void k_agg2(const float* __restrict__ h2, const int* __restrict__ csr,
                                              const int* __restrict__ row_off, const float* __restrict__ dinv,
                                              const float* __restrict__ b2, float* __restrict__ out,
                                              float* __restrict__ sum, float* __restrict__ sq, int N) {
    __shared__ float lss[256], lsq[256];
    int lane = threadIdx.x & 63;
    int wave = (blockIdx.x * blockDim.x + threadIdx.x) >> 6;
    int nw = (gridDim.x * blockDim.x) >> 6;
    int c = lane & 31;
    int half = lane >> 5;
    float bc = b2[c];
    float ls = 0.f, lq = 0.f;
    for (int v = wave; v < N; v += nw) {
        int s0 = row_off[v], s1 = row_off[v + 1];
        float acc = 0.f;
        for (int e = s0 + half; e < s1; e += 2) {
            int s = csr[e];
            acc = fmaf(dinv[s], h2[(size_t)s * 32 + c], acc);
        }
        acc += __shfl_xor(acc, 32);
        if (lane < 32) {
            float dv = dinv[v];
            float hv = h2[(size_t)v * 32 + c];
            float o = bc + dv * acc + dv * dv * hv;
            out[(size_t)v * 32 + c] = o;
            ls += o; lq += o * o;
        }
    }
    lss[threadIdx.x] = ls; lsq[threadIdx.x] = lq;
    __syncthreads();
    if (threadIdx.x < 32) {
        float s = 0.f, q = 0.f;
#pragma unroll
        for (int j = 0; j < 8; ++j) { s += lss[threadIdx.x + 32 * j]; q += lsq[threadIdx.x + 32 * j]; }
        atomicAdd(&sum[threadIdx.x], s);
        atomicAdd(&sq[threadIdx.x], q);
    }
}

// ---------------- p[v] = dinv[v] * (relu(bn2(out2[v])) @ W3) ----------------

__global__ __launch_bounds__(256) void k_h3p(const float* __restrict__ buf, const float* __restrict__ a2,
                                             const float* __restrict__ d2, const float* __restrict__ W3,
                                             const float* __restrict__ dinv, float* __restrict__ p, int N) {
    int c = threadIdx.x & 31;
    int v = blockIdx.x * 8 + (threadIdx.x >> 5);
    if (v >= N) return;
    float val = buf[(size_t)v * 32 + c];
    float r = fmaxf(fmaf(a2[c], val, d2[c]), 0.f) * W3[c];
#pragma unroll
    for (int off = 16; off >= 1; off >>= 1) r += __shfl_xor(r, off, 32);
    if (c == 0) p[v] = dinv[v] * r;
}

// ---------------- Layer 3: scalar gather-reduce ----------------

__global__ __launch_bounds__(256) void k_agg3(const float* __restrict__ p, const int* __restrict__ csr,
                                              const int* __restrict__ row_off, const float* __restrict__ dinv,
                                              const float* __restrict__ b3, float* __restrict__ out, int N) {
    int lane = threadIdx.x & 63;
    int wave = (blockIdx.x * blockDim.x + threadIdx.x) >> 6;
    int nw = (gridDim.x * blockDim.x) >> 6;
    for (int v = wave; v < N; v += nw) {
        int s0 = row_off[v], s1 = row_off[v + 1];
        float acc = 0.f;
        for (int e = s0 + lane; e < s1; e += 64) acc += p[csr[e]];
#pragma unroll
        for (int off = 32; off >= 1; off >>= 1) acc += __shfl_xor(acc, off);
        if (lane == 0) out[v] = b3[0] + dinv[v] * acc + dinv[v] * p[v];
    }
}

// ---------------- launch ----------------

extern "C" void kernel_launch(void* const* d_in, const int* in_sizes, int n_in,
                              void* d_out, int out_size, void* d_ws, size_t ws_size,
                              hipStream_t stream) {
    const float* x      = (const float*)d_in[0];
    const int*   ei     = (const int*)d_in[1];
    const float* W1     = (const float*)d_in[2];
    const float* b1     = (const float*)d_in[3];
    const float* gamma1 = (const float*)d_in[4];
    const float* beta1  = (const float*)d_in[5];
    const float* W2     = (const float*)d_in[6];
    const float* b2     = (const float*)d_in[7];
    const float* gamma2 = (const float*)d_in[8];
    const float* beta2  = (const float*)d_in[9];
    const float* W3     = (const float*)d_in[10];
    const float* b3     = (const float*)d_in[11];

    int N = out_size;             // 100000 nodes
    int E = in_sizes[1] / 2;      // 6400000 edges
    const int* srcp = ei;
    const int* dstp = ei + E;

    char* w = (char*)d_ws;
    int*   csr     = (int*)w;          w += alignup((size_t)E * 4);
    int*   cnt     = (int*)w;          w += alignup((size_t)N * 4);
    int*   row_off = (int*)w;          w += alignup((size_t)(N + 1) * 4);
    int*   cursor  = (int*)w;          w += alignup((size_t)N * 4);
    float* dinv    = (float*)w;        w += alignup((size_t)N * 4);
    float* buf1    = (float*)w;        w += alignup((size_t)N * 32 * 4);
    float* buf2    = (float*)w;        w += alignup((size_t)N * 32 * 4);
    float* pbuf    = (float*)w;        w += alignup((size_t)N * 4);
    float* stats   = (float*)w;        w += alignup(256 * 4);   // sum1,sq1,sum2,sq2 then a1,d1,a2,d2
    int*   partials= (int*)w;          w += alignup(1024 * 4);

    float* sum1 = stats, *sq1 = stats + 32, *sum2 = stats + 64, *sq2 = stats + 96;
    float* a1 = stats + 128, *d1 = stats + 160, *a2 = stats + 192, *d2 = stats + 224;

    hipMemsetAsync(cnt, 0, (size_t)N * 4, stream);
    hipMemsetAsync(stats, 0, 128 * 4, stream);

    int NB = (N + 1023) / 1024;

    k_count_p<<<1024, 256, 0, stream>>>(dstp, cnt, E, N);
    k_dinv<<<(N + 255) / 256, 256, 0, stream>>>(cnt, dinv, N);
    k_scan_a<<<NB, 256, 0, stream>>>(cnt, partials, N);
    k_scan_b<<<1, 64, 0, stream>>>(partials, row_off, NB, N);
    k_scan_c<<<NB, 256, 0, stream>>>(cnt, partials, row_off, cursor, N);
    k_fill_p<<<1024, 256, 0, stream>>>(srcp, dstp, cursor, csr, E, N);

    float invN = 1.0f / (float)N;

    k_agg1<<<1024, 256, 0, stream>>>(x, csr, row_off, dinv, W1, b1, buf1, sum1, sq1, N);
    k_bnparam<<<1, 32, 0, stream>>>(sum1, sq1, gamma1, beta1, a1, d1, invN);
    k_h2<<<(N + 7) / 8, 256, 0, stream>>>(buf1, W2, a1, d1, N);
    k_agg2<<<1024, 256, 0, stream>>>(buf1, csr, row_off, dinv, b2, buf2, sum2, sq2, N);
    k_bnparam<<<1, 32, 0, stream>>>(sum2, sq2, gamma2, beta2, a2, d2, invN);
    k_h3p<<<(N + 7) / 8, 256, 0, stream>>>(buf2, a2, d2, W3, dinv, pbuf, N);
    k_agg3<<<1024, 256, 0, stream>>>(pbuf, csr, row_off, dinv, b3, (float*)d_out, N);
}

// Round 4
// 1075.640 us; speedup vs baseline: 1.4058x; 1.1696x over previous
//
#include <hip/hip_runtime.h>
#include <hip/hip_bf16.h>

#define EPSBN 1e-5f
#define NPART 8

static __host__ __device__ inline size_t alignup(size_t x) { return (x + 255) & ~(size_t)255; }

__device__ inline float4 ld4(const float* p) { return *reinterpret_cast<const float4*>(p); }

// ---------------- CSR build (dst-range partitioned for XCD/L2 locality) ----------------

__global__ __launch_bounds__(256) void k_count_p(const int* __restrict__ dst, int* __restrict__ cnt, int E, int N) {
    int part = blockIdx.x & (NPART - 1);
    int rsz = (N + NPART - 1) / NPART;
    int lo = part * rsz;
    int hi = min(N, lo + rsz);
    int bpart = blockIdx.x >> 3;
    int nb = gridDim.x >> 3;
    int tid = bpart * blockDim.x + threadIdx.x;
    int nthr = nb * blockDim.x;
    int ngroups = E >> 2;
    for (int g = tid; g < ngroups; g += nthr) {
        int4 d = *reinterpret_cast<const int4*>(dst + (size_t)g * 4);
        if (d.x >= lo && d.x < hi) atomicAdd(&cnt[d.x], 1);
        if (d.y >= lo && d.y < hi) atomicAdd(&cnt[d.y], 1);
        if (d.z >= lo && d.z < hi) atomicAdd(&cnt[d.z], 1);
        if (d.w >= lo && d.w < hi) atomicAdd(&cnt[d.w], 1);
    }
    if (tid == 0) {
        for (int k = ngroups * 4; k < E; ++k) {
            int d = dst[k];
            if (d >= lo && d < hi) atomicAdd(&cnt[d], 1);
        }
    }
}

__global__ __launch_bounds__(256) void k_fill_p(const int* __restrict__ src, const int* __restrict__ dst,
                                                int* __restrict__ cursor, int* __restrict__ csr, int E, int N) {
    int part = blockIdx.x & (NPART - 1);
    int rsz = (N + NPART - 1) / NPART;
    int lo = part * rsz;
    int hi = min(N, lo + rsz);
    int bpart = blockIdx.x >> 3;
    int nb = gridDim.x >> 3;
    int tid = bpart * blockDim.x + threadIdx.x;
    int nthr = nb * blockDim.x;
    int ngroups = E >> 2;
    for (int g = tid; g < ngroups; g += nthr) {
        int4 d = *reinterpret_cast<const int4*>(dst + (size_t)g * 4);
        bool bx = (d.x >= lo && d.x < hi);
        bool by = (d.y >= lo && d.y < hi);
        bool bz = (d.z >= lo && d.z < hi);
        bool bw = (d.w >= lo && d.w < hi);
        if (bx || by || bz || bw) {
            int4 s = *reinterpret_cast<const int4*>(src + (size_t)g * 4);
            int p;
            if (bx) { p = atomicAdd(&cursor[d.x], 1); if (p < E) csr[p] = s.x; }
            if (by) { p = atomicAdd(&cursor[d.y], 1); if (p < E) csr[p] = s.y; }
            if (bz) { p = atomicAdd(&cursor[d.z], 1); if (p < E) csr[p] = s.z; }
            if (bw) { p = atomicAdd(&cursor[d.w], 1); if (p < E) csr[p] = s.w; }
        }
    }
    if (tid == 0) {
        for (int k = ngroups * 4; k < E; ++k) {
            int d = dst[k];
            if (d >= lo && d < hi) {
                int p = atomicAdd(&cursor[d], 1);
                if (p < E) csr[p] = src[k];
            }
        }
    }
}

__global__ __launch_bounds__(256) void k_dinv(const int* __restrict__ cnt, float* __restrict__ dinv, int N) {
    int v = blockIdx.x * blockDim.x + threadIdx.x;
    if (v < N) dinv[v] = rsqrtf((float)(cnt[v] + 1));   // +1 self-loop
}

// xs[v] = dinv[v] * x[v]  (pre-scale so gather loops need no dinv[s] load)
__global__ __launch_bounds__(256) void k_xs(const float* __restrict__ x, const float* __restrict__ dinv,
                                            float* __restrict__ xs, int N) {
    int v = blockIdx.x * blockDim.x + threadIdx.x;
    if (v < N) {
        float w = dinv[v];
        const float* xp = x + (size_t)v * 5;
        float* op = xs + (size_t)v * 5;
        op[0] = w * xp[0]; op[1] = w * xp[1]; op[2] = w * xp[2];
        op[3] = w * xp[3]; op[4] = w * xp[4];
    }
}

__global__ __launch_bounds__(256) void k_scan_a(const int* __restrict__ cnt, int* __restrict__ partials, int N) {
    __shared__ int lds[256];
    int i0 = blockIdx.x * 1024 + threadIdx.x * 4;
    int s = 0;
#pragma unroll
    for (int k = 0; k < 4; ++k) if (i0 + k < N) s += cnt[i0 + k];
    lds[threadIdx.x] = s;
    __syncthreads();
    for (int off = 128; off >= 1; off >>= 1) {
        if ((int)threadIdx.x < off) lds[threadIdx.x] += lds[threadIdx.x + off];
        __syncthreads();
    }
    if (threadIdx.x == 0) partials[blockIdx.x] = lds[0];
}

__global__ void k_scan_b(int* __restrict__ partials, int* __restrict__ row_off, int NB, int N) {
    if (threadIdx.x == 0 && blockIdx.x == 0) {
        int run = 0;
        for (int i = 0; i < NB; ++i) { int t = partials[i]; partials[i] = run; run += t; }
        row_off[N] = run;
    }
}

__global__ __launch_bounds__(256) void k_scan_c(const int* __restrict__ cnt, const int* __restrict__ partials,
                                                int* __restrict__ row_off, int* __restrict__ cursor, int N) {
    __shared__ int lds[256];
    int b = blockIdx.x;
    int base = partials[b];
    int i0 = b * 1024 + threadIdx.x * 4;
    int v[4];
#pragma unroll
    for (int k = 0; k < 4; ++k) v[k] = (i0 + k < N) ? cnt[i0 + k] : 0;
    int tsum = v[0] + v[1] + v[2] + v[3];
    lds[threadIdx.x] = tsum;
    __syncthreads();
    for (int off = 1; off < 256; off <<= 1) {
        int t = ((int)threadIdx.x >= off) ? lds[threadIdx.x - off] : 0;
        __syncthreads();
        lds[threadIdx.x] += t;
        __syncthreads();
    }
    int run = lds[threadIdx.x] - tsum + base;   // exclusive prefix
#pragma unroll
    for (int k = 0; k < 4; ++k) {
        if (i0 + k < N) { row_off[i0 + k] = run; cursor[i0 + k] = run; run += v[k]; }
    }
}

// ---------------- Layer 1: aggregate pre-scaled 5-dim xs, matmul 5->32, BN1 stats ----------------

__global__ __launch_bounds__(256) void k_agg1(const float* __restrict__ xs, const int* __restrict__ csr,
                                              const int* __restrict__ row_off, const float* __restrict__ dinv,
                                              const float* __restrict__ W1, const float* __restrict__ b1,
                                              float* __restrict__ out, float* __restrict__ sum, float* __restrict__ sq,
                                              int N) {
    __shared__ float lss[256], lsq[256];
    int lane = threadIdx.x & 63;
    int wave = (blockIdx.x * blockDim.x + threadIdx.x) >> 6;
    int nw = (gridDim.x * blockDim.x) >> 6;
    int c = lane & 31;
    float w0 = W1[c], w1 = W1[32 + c], w2 = W1[64 + c], w3 = W1[96 + c], w4 = W1[128 + c];
    float bc = b1[c];
    float ls = 0.f, lq = 0.f;
    for (int v = wave; v < N; v += nw) {
        int s0 = row_off[v], s1 = row_off[v + 1];
        float a0 = 0, a1 = 0, a2 = 0, a3 = 0, a4 = 0;
        int e = s0 + lane;
        for (; e + 64 < s1; e += 128) {
            int sA = csr[e], sB = csr[e + 64];
            const float* pa = xs + (size_t)sA * 5;
            const float* pb = xs + (size_t)sB * 5;
            a0 += pa[0] + pb[0]; a1 += pa[1] + pb[1]; a2 += pa[2] + pb[2];
            a3 += pa[3] + pb[3]; a4 += pa[4] + pb[4];
        }
        if (e < s1) {
            const float* pa = xs + (size_t)csr[e] * 5;
            a0 += pa[0]; a1 += pa[1]; a2 += pa[2]; a3 += pa[3]; a4 += pa[4];
        }
#pragma unroll
        for (int off = 32; off >= 1; off >>= 1) {
            a0 += __shfl_xor(a0, off);
            a1 += __shfl_xor(a1, off);
            a2 += __shfl_xor(a2, off);
            a3 += __shfl_xor(a3, off);
            a4 += __shfl_xor(a4, off);
        }
        if (lane < 32) {
            float dv = dinv[v];
            const float* xv = xs + (size_t)v * 5;
            float t0 = dv * (a0 + xv[0]);
            float t1 = dv * (a1 + xv[1]);
            float t2 = dv * (a2 + xv[2]);
            float t3 = dv * (a3 + xv[3]);
            float t4 = dv * (a4 + xv[4]);
            float h = bc;
            h = fmaf(t0, w0, h); h = fmaf(t1, w1, h); h = fmaf(t2, w2, h);
            h = fmaf(t3, w3, h); h = fmaf(t4, w4, h);
            out[(size_t)v * 32 + c] = h;
            ls += h; lq += h * h;
        }
    }
    lss[threadIdx.x] = ls; lsq[threadIdx.x] = lq;
    __syncthreads();
    if (threadIdx.x < 32) {
        float s = 0.f, q = 0.f;
#pragma unroll
        for (int j = 0; j < 8; ++j) { s += lss[threadIdx.x + 32 * j]; q += lsq[threadIdx.x + 32 * j]; }
        atomicAdd(&sum[threadIdx.x], s);
        atomicAdd(&sq[threadIdx.x], q);
    }
}

// ---------------- BN params ----------------

__global__ void k_bnparam(const float* __restrict__ sum, const float* __restrict__ sq,
                          const float* __restrict__ gamma, const float* __restrict__ beta,
                          float* __restrict__ aOut, float* __restrict__ dOut, float invN) {
    int c = threadIdx.x;
    if (c < 32) {
        float mean = sum[c] * invN;
        float var = fmaxf(sq[c] * invN - mean * mean, 0.f);
        float rinv = rsqrtf(var + EPSBN);
        float a = gamma[c] * rinv;
        aOut[c] = a;
        dOut[c] = beta[c] - mean * a;
    }
}

// ---------------- h2' = dinv[v] * (relu(bn1(out1)) @ W2), in place ----------------

__global__ __launch_bounds__(256) void k_h2(float* __restrict__ buf, const float* __restrict__ W2,
                                            const float* __restrict__ a1, const float* __restrict__ d1,
                                            const float* __restrict__ dinv, int N) {
    __shared__ float W2s[1024];
    __shared__ float rbuf[8][33];
    for (int i = threadIdx.x; i < 1024; i += 256) W2s[i] = W2[i];
    int g = threadIdx.x >> 5, c = threadIdx.x & 31;
    int v = blockIdx.x * 8 + g;
    float r = 0.f;
    if (v < N) {
        float val = buf[(size_t)v * 32 + c];
        r = fmaxf(fmaf(a1[c], val, d1[c]), 0.f);
    }
    __syncthreads();
    rbuf[g][c] = r;
    __syncthreads();
    if (v < N) {
        float h = 0.f;
#pragma unroll
        for (int k = 0; k < 32; ++k) h = fmaf(rbuf[g][k], W2s[k * 32 + c], h);
        buf[(size_t)v * 32 + c] = h * dinv[v];
    }
}

// ---------------- Layer 2: gather pre-scaled h2' rows; 8 edges in flight/wave ----------------

__global__ __launch_bounds__(256) void k_agg2(const float* __restrict__ h2s, const int* __restrict__ csr,
                                              const int* __restrict__ row_off, const float* __restrict__ dinv,
                                              const float* __restrict__ b2, float* __restrict__ out,
                                              float* __restrict__ sum, float* __restrict__ sq, int N) {
    __shared__ float4 lss[256], lsq[256];
    int lane = threadIdx.x & 63;
    int g = lane >> 3;       // 8 groups, one edge each per iter
    int q = lane & 7;        // float4 slot: channels q*4 .. q*4+3
    int wave = (blockIdx.x * blockDim.x + threadIdx.x) >> 6;
    int nw = (gridDim.x * blockDim.x) >> 6;
    float4 bc = reinterpret_cast<const float4*>(b2)[q];
    float4 ls = {0, 0, 0, 0}, lq = {0, 0, 0, 0};
    for (int v = wave; v < N; v += nw) {
        int s0 = row_off[v], s1 = row_off[v + 1];
        float4 acc = {0, 0, 0, 0};
        int e = s0 + g;
        for (; e + 8 < s1; e += 16) {
            int sA = csr[e], sB = csr[e + 8];
            float4 ra = ld4(h2s + (size_t)sA * 32 + q * 4);
            float4 rb = ld4(h2s + (size_t)sB * 32 + q * 4);
            acc.x += ra.x + rb.x; acc.y += ra.y + rb.y;
            acc.z += ra.z + rb.z; acc.w += ra.w + rb.w;
        }
        if (e < s1) {
            float4 ra = ld4(h2s + (size_t)csr[e] * 32 + q * 4);
            acc.x += ra.x; acc.y += ra.y; acc.z += ra.z; acc.w += ra.w;
        }
#pragma unroll
        for (int off = 8; off <= 32; off <<= 1) {
            acc.x += __shfl_xor(acc.x, off);
            acc.y += __shfl_xor(acc.y, off);
            acc.z += __shfl_xor(acc.z, off);
            acc.w += __shfl_xor(acc.w, off);
        }
        if (lane < 8) {
            float dv = dinv[v];
            float4 hv = ld4(h2s + (size_t)v * 32 + q * 4);   // already dinv[v]*h2
            float4 o;
            o.x = fmaf(dv, acc.x + hv.x, bc.x);
            o.y = fmaf(dv, acc.y + hv.y, bc.y);
            o.z = fmaf(dv, acc.z + hv.z, bc.z);
            o.w = fmaf(dv, acc.w + hv.w, bc.w);
            *reinterpret_cast<float4*>(out + (size_t)v * 32 + q * 4) = o;
            ls.x += o.x; ls.y += o.y; ls.z += o.z; ls.w += o.w;
            lq.x += o.x * o.x; lq.y += o.y * o.y; lq.z += o.z * o.z; lq.w += o.w * o.w;
        }
    }
    lss[threadIdx.x] = ls; lsq[threadIdx.x] = lq;
    __syncthreads();
    if (threadIdx.x < 8) {
        float4 s = {0, 0, 0, 0}, t = {0, 0, 0, 0};
#pragma unroll
        for (int wv = 0; wv < 4; ++wv) {
            float4 a = lss[wv * 64 + threadIdx.x];
            float4 b = lsq[wv * 64 + threadIdx.x];
            s.x += a.x; s.y += a.y; s.z += a.z; s.w += a.w;
            t.x += b.x; t.y += b.y; t.z += b.z; t.w += b.w;
        }
        int c0 = threadIdx.x * 4;
        atomicAdd(&sum[c0 + 0], s.x); atomicAdd(&sum[c0 + 1], s.y);
        atomicAdd(&sum[c0 + 2], s.z); atomicAdd(&sum[c0 + 3], s.w);
        atomicAdd(&sq[c0 + 0], t.x);  atomicAdd(&sq[c0 + 1], t.y);
        atomicAdd(&sq[c0 + 2], t.z);  atomicAdd(&sq[c0 + 3], t.w);
    }
}

// ---------------- p[v] = dinv[v] * (relu(bn2(out2[v])) @ W3) ----------------

__global__ __launch_bounds__(256) void k_h3p(const float* __restrict__ buf, const float* __restrict__ a2,
                                             const float* __restrict__ d2, const float* __restrict__ W3,
                                             const float* __restrict__ dinv, float* __restrict__ p, int N) {
    int c = threadIdx.x & 31;
    int v = blockIdx.x * 8 + (threadIdx.x >> 5);
    if (v >= N) return;
    float val = buf[(size_t)v * 32 + c];
    float r = fmaxf(fmaf(a2[c], val, d2[c]), 0.f) * W3[c];
#pragma unroll
    for (int off = 16; off >= 1; off >>= 1) r += __shfl_xor(r, off, 32);
    if (c == 0) p[v] = dinv[v] * r;
}

// ---------------- Layer 3: scalar gather-reduce ----------------

__global__ __launch_bounds__(256) void k_agg3(const float* __restrict__ p, const int* __restrict__ csr,
                                              const int* __restrict__ row_off, const float* __restrict__ dinv,
                                              const float* __restrict__ b3, float* __restrict__ out, int N) {
    int lane = threadIdx.x & 63;
    int wave = (blockIdx.x * blockDim.x + threadIdx.x) >> 6;
    int nw = (gridDim.x * blockDim.x) >> 6;
    for (int v = wave; v < N; v += nw) {
        int s0 = row_off[v], s1 = row_off[v + 1];
        float acc = 0.f;
        int e = s0 + lane;
        for (; e + 64 < s1; e += 128) acc += p[csr[e]] + p[csr[e + 64]];
        if (e < s1) acc += p[csr[e]];
#pragma unroll
        for (int off = 32; off >= 1; off >>= 1) acc += __shfl_xor(acc, off);
        if (lane == 0) out[v] = fmaf(dinv[v], acc + p[v], b3[0]);
    }
}

// ---------------- launch ----------------

extern "C" void kernel_launch(void* const* d_in, const int* in_sizes, int n_in,
                              void* d_out, int out_size, void* d_ws, size_t ws_size,
                              hipStream_t stream) {
    const float* x      = (const float*)d_in[0];
    const int*   ei     = (const int*)d_in[1];
    const float* W1     = (const float*)d_in[2];
    const float* b1     = (const float*)d_in[3];
    const float* gamma1 = (const float*)d_in[4];
    const float* beta1  = (const float*)d_in[5];
    const float* W2     = (const float*)d_in[6];
    const float* b2     = (const float*)d_in[7];
    const float* gamma2 = (const float*)d_in[8];
    const float* beta2  = (const float*)d_in[9];
    const float* W3     = (const float*)d_in[10];
    const float* b3     = (const float*)d_in[11];

    int N = out_size;             // 100000 nodes
    int E = in_sizes[1] / 2;      // 6400000 edges
    const int* srcp = ei;
    const int* dstp = ei + E;

    char* w = (char*)d_ws;
    int*   csr     = (int*)w;          w += alignup((size_t)E * 4);
    int*   cnt     = (int*)w;          w += alignup((size_t)N * 4);
    int*   row_off = (int*)w;          w += alignup((size_t)(N + 1) * 4);
    int*   cursor  = (int*)w;          w += alignup((size_t)N * 4);
    float* dinv    = (float*)w;        w += alignup((size_t)N * 4);
    float* xs      = (float*)w;        w += alignup((size_t)N * 5 * 4);
    float* buf1    = (float*)w;        w += alignup((size_t)N * 32 * 4);
    float* buf2    = (float*)w;        w += alignup((size_t)N * 32 * 4);
    float* pbuf    = (float*)w;        w += alignup((size_t)N * 4);
    float* stats   = (float*)w;        w += alignup(256 * 4);
    int*   partials= (int*)w;          w += alignup(1024 * 4);

    float* sum1 = stats, *sq1 = stats + 32, *sum2 = stats + 64, *sq2 = stats + 96;
    float* a1 = stats + 128, *d1 = stats + 160, *a2 = stats + 192, *d2 = stats + 224;

    hipMemsetAsync(cnt, 0, (size_t)N * 4, stream);
    hipMemsetAsync(stats, 0, 128 * 4, stream);

    int NB = (N + 1023) / 1024;

    k_count_p<<<2048, 256, 0, stream>>>(dstp, cnt, E, N);
    k_dinv<<<(N + 255) / 256, 256, 0, stream>>>(cnt, dinv, N);
    k_xs<<<(N + 255) / 256, 256, 0, stream>>>(x, dinv, xs, N);
    k_scan_a<<<NB, 256, 0, stream>>>(cnt, partials, N);
    k_scan_b<<<1, 64, 0, stream>>>(partials, row_off, NB, N);
    k_scan_c<<<NB, 256, 0, stream>>>(cnt, partials, row_off, cursor, N);
    k_fill_p<<<2048, 256, 0, stream>>>(srcp, dstp, cursor, csr, E, N);

    float invN = 1.0f / (float)N;

    k_agg1<<<2048, 256, 0, stream>>>(xs, csr, row_off, dinv, W1, b1, buf1, sum1, sq1, N);
    k_bnparam<<<1, 32, 0, stream>>>(sum1, sq1, gamma1, beta1, a1, d1, invN);
    k_h2<<<(N + 7) / 8, 256, 0, stream>>>(buf1, W2, a1, d1, dinv, N);
    k_agg2<<<2048, 256, 0, stream>>>(buf1, csr, row_off, dinv, b2, buf2, sum2, sq2, N);
    k_bnparam<<<1, 32, 0, stream>>>(sum2, sq2, gamma2, beta2, a2, d2, invN);
    k_h3p<<<(N + 7) / 8, 256, 0, stream>>>(buf2, a2, d2, W3, dinv, pbuf, N);
    k_agg3<<<2048, 256, 0, stream>>>(pbuf, csr, row_off, dinv, b3, (float*)d_out, N);
}

// Round 5
// 938.398 us; speedup vs baseline: 1.6114x; 1.1463x over previous
//
#include <hip/hip_runtime.h>
#include <hip/hip_bf16.h>
#include <hip/hip_fp16.h>

#define EPSBN 1e-5f
#define NPART 8

static __host__ __device__ inline size_t alignup(size_t x) { return (x + 255) & ~(size_t)255; }

__device__ inline float4 ld4(const float* p) { return *reinterpret_cast<const float4*>(p); }
__device__ inline float2 h2f(unsigned int b) {
    __half2 h = *reinterpret_cast<__half2*>(&b);
    return __half22float2(h);
}

// ---------------- CSR build (dst-range partitioned for XCD/L2 locality) ----------------

__global__ __launch_bounds__(256) void k_count_p(const int* __restrict__ dst, int* __restrict__ cnt, int E, int N) {
    int part = blockIdx.x & (NPART - 1);
    int rsz = (N + NPART - 1) / NPART;
    int lo = part * rsz;
    int hi = min(N, lo + rsz);
    int bpart = blockIdx.x >> 3;
    int nb = gridDim.x >> 3;
    int tid = bpart * blockDim.x + threadIdx.x;
    int nthr = nb * blockDim.x;
    int ngroups = E >> 2;
    for (int g = tid; g < ngroups; g += nthr) {
        int4 d = *reinterpret_cast<const int4*>(dst + (size_t)g * 4);
        if (d.x >= lo && d.x < hi) atomicAdd(&cnt[d.x], 1);
        if (d.y >= lo && d.y < hi) atomicAdd(&cnt[d.y], 1);
        if (d.z >= lo && d.z < hi) atomicAdd(&cnt[d.z], 1);
        if (d.w >= lo && d.w < hi) atomicAdd(&cnt[d.w], 1);
    }
    if (tid == 0) {
        for (int k = ngroups * 4; k < E; ++k) {
            int d = dst[k];
            if (d >= lo && d < hi) atomicAdd(&cnt[d], 1);
        }
    }
}

__global__ __launch_bounds__(256) void k_fill_p(const int* __restrict__ src, const int* __restrict__ dst,
                                                int* __restrict__ cursor, int* __restrict__ csr, int E, int N) {
    int part = blockIdx.x & (NPART - 1);
    int rsz = (N + NPART - 1) / NPART;
    int lo = part * rsz;
    int hi = min(N, lo + rsz);
    int bpart = blockIdx.x >> 3;
    int nb = gridDim.x >> 3;
    int tid = bpart * blockDim.x + threadIdx.x;
    int nthr = nb * blockDim.x;
    int ngroups = E >> 2;
    for (int g = tid; g < ngroups; g += nthr) {
        int4 d = *reinterpret_cast<const int4*>(dst + (size_t)g * 4);
        bool bx = (d.x >= lo && d.x < hi);
        bool by = (d.y >= lo && d.y < hi);
        bool bz = (d.z >= lo && d.z < hi);
        bool bw = (d.w >= lo && d.w < hi);
        if (bx || by || bz || bw) {
            int4 s = *reinterpret_cast<const int4*>(src + (size_t)g * 4);
            int p;
            if (bx) { p = atomicAdd(&cursor[d.x], 1); if (p < E) csr[p] = s.x; }
            if (by) { p = atomicAdd(&cursor[d.y], 1); if (p < E) csr[p] = s.y; }
            if (bz) { p = atomicAdd(&cursor[d.z], 1); if (p < E) csr[p] = s.z; }
            if (bw) { p = atomicAdd(&cursor[d.w], 1); if (p < E) csr[p] = s.w; }
        }
    }
    if (tid == 0) {
        for (int k = ngroups * 4; k < E; ++k) {
            int d = dst[k];
            if (d >= lo && d < hi) {
                int p = atomicAdd(&cursor[d], 1);
                if (p < E) csr[p] = src[k];
            }
        }
    }
}

__global__ __launch_bounds__(256) void k_dinv(const int* __restrict__ cnt, float* __restrict__ dinv, int N) {
    int v = blockIdx.x * blockDim.x + threadIdx.x;
    if (v < N) dinv[v] = rsqrtf((float)(cnt[v] + 1));   // +1 self-loop
}

// xs_h[v] = fp16( dinv[v] * x[v] ), padded to 8 halves = 16 B/row (one dwordx4 per gather)
__global__ __launch_bounds__(256) void k_xs(const float* __restrict__ x, const float* __restrict__ dinv,
                                            uint4* __restrict__ xs_h, int N) {
    int v = blockIdx.x * blockDim.x + threadIdx.x;
    if (v < N) {
        float w = dinv[v];
        const float* xp = x + (size_t)v * 5;
        __half hs[8];
#pragma unroll
        for (int k = 0; k < 5; ++k) hs[k] = __float2half(w * xp[k]);
        hs[5] = hs[6] = hs[7] = __float2half(0.f);
        xs_h[v] = *reinterpret_cast<uint4*>(hs);
    }
}

__global__ __launch_bounds__(256) void k_scan_a(const int* __restrict__ cnt, int* __restrict__ partials, int N) {
    __shared__ int lds[256];
    int i0 = blockIdx.x * 1024 + threadIdx.x * 4;
    int s = 0;
#pragma unroll
    for (int k = 0; k < 4; ++k) if (i0 + k < N) s += cnt[i0 + k];
    lds[threadIdx.x] = s;
    __syncthreads();
    for (int off = 128; off >= 1; off >>= 1) {
        if ((int)threadIdx.x < off) lds[threadIdx.x] += lds[threadIdx.x + off];
        __syncthreads();
    }
    if (threadIdx.x == 0) partials[blockIdx.x] = lds[0];
}

__global__ void k_scan_b(int* __restrict__ partials, int* __restrict__ row_off, int NB, int N) {
    if (threadIdx.x == 0 && blockIdx.x == 0) {
        int run = 0;
        for (int i = 0; i < NB; ++i) { int t = partials[i]; partials[i] = run; run += t; }
        row_off[N] = run;
    }
}

__global__ __launch_bounds__(256) void k_scan_c(const int* __restrict__ cnt, const int* __restrict__ partials,
                                                int* __restrict__ row_off, int* __restrict__ cursor, int N) {
    __shared__ int lds[256];
    int b = blockIdx.x;
    int base = partials[b];
    int i0 = b * 1024 + threadIdx.x * 4;
    int v[4];
#pragma unroll
    for (int k = 0; k < 4; ++k) v[k] = (i0 + k < N) ? cnt[i0 + k] : 0;
    int tsum = v[0] + v[1] + v[2] + v[3];
    lds[threadIdx.x] = tsum;
    __syncthreads();
    for (int off = 1; off < 256; off <<= 1) {
        int t = ((int)threadIdx.x >= off) ? lds[threadIdx.x - off] : 0;
        __syncthreads();
        lds[threadIdx.x] += t;
        __syncthreads();
    }
    int run = lds[threadIdx.x] - tsum + base;   // exclusive prefix
#pragma unroll
    for (int k = 0; k < 4; ++k) {
        if (i0 + k < N) { row_off[i0 + k] = run; cursor[i0 + k] = run; run += v[k]; }
    }
}

// ---------------- Layer 1: one 16B fp16 row per edge per lane; matmul 5->32; BN1 stats ----------------

__global__ __launch_bounds__(256) void k_agg1(const uint4* __restrict__ xs_h, const int* __restrict__ csr,
                                              const int* __restrict__ row_off, const float* __restrict__ dinv,
                                              const float* __restrict__ W1, const float* __restrict__ b1,
                                              float* __restrict__ out, float* __restrict__ sum, float* __restrict__ sq,
                                              int N) {
    __shared__ float lss[256], lsq[256];
    int lane = threadIdx.x & 63;
    int wave = (blockIdx.x * blockDim.x + threadIdx.x) >> 6;
    int nw = (gridDim.x * blockDim.x) >> 6;
    int c = lane & 31;
    float w0 = W1[c], w1 = W1[32 + c], w2 = W1[64 + c], w3 = W1[96 + c], w4 = W1[128 + c];
    float bc = b1[c];
    float ls = 0.f, lq = 0.f;
    for (int v = wave; v < N; v += nw) {
        int s0 = row_off[v], s1 = row_off[v + 1];
        float a0 = 0, a1 = 0, a2 = 0, a3 = 0, a4 = 0;
        int e = s0 + lane;
        for (; e + 64 < s1; e += 128) {
            uint4 ua = xs_h[csr[e]];
            uint4 ub = xs_h[csr[e + 64]];
            float2 f;
            f = h2f(ua.x); a0 += f.x; a1 += f.y;
            f = h2f(ua.y); a2 += f.x; a3 += f.y;
            f = h2f(ua.z); a4 += f.x;
            f = h2f(ub.x); a0 += f.x; a1 += f.y;
            f = h2f(ub.y); a2 += f.x; a3 += f.y;
            f = h2f(ub.z); a4 += f.x;
        }
        if (e < s1) {
            uint4 ua = xs_h[csr[e]];
            float2 f;
            f = h2f(ua.x); a0 += f.x; a1 += f.y;
            f = h2f(ua.y); a2 += f.x; a3 += f.y;
            f = h2f(ua.z); a4 += f.x;
        }
#pragma unroll
        for (int off = 32; off >= 1; off >>= 1) {
            a0 += __shfl_xor(a0, off);
            a1 += __shfl_xor(a1, off);
            a2 += __shfl_xor(a2, off);
            a3 += __shfl_xor(a3, off);
            a4 += __shfl_xor(a4, off);
        }
        if (lane < 32) {
            float dv = dinv[v];
            uint4 uv = xs_h[v];
            float2 f0 = h2f(uv.x), f1 = h2f(uv.y), f2v = h2f(uv.z);
            float t0 = dv * (a0 + f0.x);
            float t1 = dv * (a1 + f0.y);
            float t2 = dv * (a2 + f1.x);
            float t3 = dv * (a3 + f1.y);
            float t4 = dv * (a4 + f2v.x);
            float h = bc;
            h = fmaf(t0, w0, h); h = fmaf(t1, w1, h); h = fmaf(t2, w2, h);
            h = fmaf(t3, w3, h); h = fmaf(t4, w4, h);
            out[(size_t)v * 32 + c] = h;
            ls += h; lq += h * h;
        }
    }
    lss[threadIdx.x] = ls; lsq[threadIdx.x] = lq;
    __syncthreads();
    if (threadIdx.x < 32) {
        float s = 0.f, q = 0.f;
#pragma unroll
        for (int j = 0; j < 8; ++j) { s += lss[threadIdx.x + 32 * j]; q += lsq[threadIdx.x + 32 * j]; }
        atomicAdd(&sum[threadIdx.x], s);
        atomicAdd(&sq[threadIdx.x], q);
    }
}

// ---------------- BN params ----------------

__global__ void k_bnparam(const float* __restrict__ sum, const float* __restrict__ sq,
                          const float* __restrict__ gamma, const float* __restrict__ beta,
                          float* __restrict__ aOut, float* __restrict__ dOut, float invN) {
    int c = threadIdx.x;
    if (c < 32) {
        float mean = sum[c] * invN;
        float var = fmaxf(sq[c] * invN - mean * mean, 0.f);
        float rinv = rsqrtf(var + EPSBN);
        float a = gamma[c] * rinv;
        aOut[c] = a;
        dOut[c] = beta[c] - mean * a;
    }
}

// ---------------- h2h = fp16( dinv[v] * (relu(bn1(bufIn)) @ W2) ) ----------------

__global__ __launch_bounds__(256) void k_h2(const float* __restrict__ bufIn, const float* __restrict__ W2,
                                            const float* __restrict__ a1, const float* __restrict__ d1,
                                            const float* __restrict__ dinv, __half* __restrict__ h2h, int N) {
    __shared__ float W2s[1024];
    __shared__ float rbuf[8][33];
    for (int i = threadIdx.x; i < 1024; i += 256) W2s[i] = W2[i];
    int g = threadIdx.x >> 5, c = threadIdx.x & 31;
    int v = blockIdx.x * 8 + g;
    float r = 0.f;
    if (v < N) {
        float val = bufIn[(size_t)v * 32 + c];
        r = fmaxf(fmaf(a1[c], val, d1[c]), 0.f);
    }
    __syncthreads();
    rbuf[g][c] = r;
    __syncthreads();
    if (v < N) {
        float h = 0.f;
#pragma unroll
        for (int k = 0; k < 32; ++k) h = fmaf(rbuf[g][k], W2s[k * 32 + c], h);
        h2h[(size_t)v * 32 + c] = __float2half(h * dinv[v]);
    }
}

// ---------------- Layer 2: fp16 row gather, 4 lanes/row (16B each), 16 rows/wave-iter ----------------

__global__ __launch_bounds__(256) void k_agg2(const uint4* __restrict__ h2h4, const int* __restrict__ csr,
                                              const int* __restrict__ row_off, const float* __restrict__ dinv,
                                              const float* __restrict__ b2, float* __restrict__ out,
                                              float* __restrict__ sum, float* __restrict__ sq, int N) {
    __shared__ float lssum[128], lssq[128];
    int lane = threadIdx.x & 63;
    int g = lane >> 2;       // 16 groups, one row each per iter
    int q = lane & 3;        // 16B slot: channels q*8 .. q*8+7
    int wave = (blockIdx.x * blockDim.x + threadIdx.x) >> 6;
    int nw = (gridDim.x * blockDim.x) >> 6;
    float bcv[8];
#pragma unroll
    for (int j = 0; j < 8; ++j) bcv[j] = b2[q * 8 + j];
    float ls[8], lq[8];
#pragma unroll
    for (int j = 0; j < 8; ++j) { ls[j] = 0.f; lq[j] = 0.f; }
    for (int v = wave; v < N; v += nw) {
        int s0 = row_off[v], s1 = row_off[v + 1];
        float acc[8];
#pragma unroll
        for (int j = 0; j < 8; ++j) acc[j] = 0.f;
        int e = s0 + g;
        for (; e + 16 < s1; e += 32) {
            int sA = csr[e], sB = csr[e + 16];
            uint4 ua = h2h4[(size_t)sA * 4 + q];
            uint4 ub = h2h4[(size_t)sB * 4 + q];
            float2 f;
            f = h2f(ua.x); acc[0] += f.x; acc[1] += f.y;
            f = h2f(ua.y); acc[2] += f.x; acc[3] += f.y;
            f = h2f(ua.z); acc[4] += f.x; acc[5] += f.y;
            f = h2f(ua.w); acc[6] += f.x; acc[7] += f.y;
            f = h2f(ub.x); acc[0] += f.x; acc[1] += f.y;
            f = h2f(ub.y); acc[2] += f.x; acc[3] += f.y;
            f = h2f(ub.z); acc[4] += f.x; acc[5] += f.y;
            f = h2f(ub.w); acc[6] += f.x; acc[7] += f.y;
        }
        if (e < s1) {
            uint4 ua = h2h4[(size_t)csr[e] * 4 + q];
            float2 f;
            f = h2f(ua.x); acc[0] += f.x; acc[1] += f.y;
            f = h2f(ua.y); acc[2] += f.x; acc[3] += f.y;
            f = h2f(ua.z); acc[4] += f.x; acc[5] += f.y;
            f = h2f(ua.w); acc[6] += f.x; acc[7] += f.y;
        }
#pragma unroll
        for (int off = 4; off <= 32; off <<= 1) {
#pragma unroll
            for (int j = 0; j < 8; ++j) acc[j] += __shfl_xor(acc[j], off);
        }
        if (lane < 4) {
            float dv = dinv[v];
            uint4 uv = h2h4[(size_t)v * 4 + q];   // already dinv[v]*h2
            float hv[8];
            float2 f;
            f = h2f(uv.x); hv[0] = f.x; hv[1] = f.y;
            f = h2f(uv.y); hv[2] = f.x; hv[3] = f.y;
            f = h2f(uv.z); hv[4] = f.x; hv[5] = f.y;
            f = h2f(uv.w); hv[6] = f.x; hv[7] = f.y;
            float o[8];
#pragma unroll
            for (int j = 0; j < 8; ++j) {
                o[j] = fmaf(dv, acc[j] + hv[j], bcv[j]);
                ls[j] += o[j]; lq[j] += o[j] * o[j];
            }
            float4 o0 = {o[0], o[1], o[2], o[3]};
            float4 o1 = {o[4], o[5], o[6], o[7]};
            *reinterpret_cast<float4*>(out + (size_t)v * 32 + q * 8) = o0;
            *reinterpret_cast<float4*>(out + (size_t)v * 32 + q * 8 + 4) = o1;
        }
    }
    int wib = threadIdx.x >> 6;
    if (lane < 4) {
#pragma unroll
        for (int j = 0; j < 8; ++j) {
            lssum[wib * 32 + q * 8 + j] = ls[j];
            lssq[wib * 32 + q * 8 + j] = lq[j];
        }
    }
    __syncthreads();
    if (threadIdx.x < 32) {
        float s = lssum[threadIdx.x] + lssum[32 + threadIdx.x] + lssum[64 + threadIdx.x] + lssum[96 + threadIdx.x];
        float t = lssq[threadIdx.x] + lssq[32 + threadIdx.x] + lssq[64 + threadIdx.x] + lssq[96 + threadIdx.x];
        atomicAdd(&sum[threadIdx.x], s);
        atomicAdd(&sq[threadIdx.x], t);
    }
}

// ---------------- p[v] = dinv[v] * (relu(bn2(buf[v])) @ W3) ----------------

__global__ __launch_bounds__(256) void k_h3p(const float* __restrict__ buf, const float* __restrict__ a2,
                                             const float* __restrict__ d2, const float* __restrict__ W3,
                                             const float* __restrict__ dinv, float* __restrict__ p, int N) {
    int c = threadIdx.x & 31;
    int v = blockIdx.x * 8 + (threadIdx.x >> 5);
    if (v >= N) return;
    float val = buf[(size_t)v * 32 + c];
    float r = fmaxf(fmaf(a2[c], val, d2[c]), 0.f) * W3[c];
#pragma unroll
    for (int off = 16; off >= 1; off >>= 1) r += __shfl_xor(r, off, 32);
    if (c == 0) p[v] = dinv[v] * r;
}

// ---------------- Layer 3: scalar gather-reduce ----------------

__global__ __launch_bounds__(256) void k_agg3(const float* __restrict__ p, const int* __restrict__ csr,
                                              const int* __restrict__ row_off, const float* __restrict__ dinv,
                                              const float* __restrict__ b3, float* __restrict__ out, int N) {
    int lane = threadIdx.x & 63;
    int wave = (blockIdx.x * blockDim.x + threadIdx.x) >> 6;
    int nw = (gridDim.x * blockDim.x) >> 6;
    for (int v = wave; v < N; v += nw) {
        int s0 = row_off[v], s1 = row_off[v + 1];
        float acc = 0.f;
        int e = s0 + lane;
        for (; e + 64 < s1; e += 128) acc += p[csr[e]] + p[csr[e + 64]];
        if (e < s1) acc += p[csr[e]];
#pragma unroll
        for (int off = 32; off >= 1; off >>= 1) acc += __shfl_xor(acc, off);
        if (lane == 0) out[v] = fmaf(dinv[v], acc + p[v], b3[0]);
    }
}

// ---------------- launch ----------------

extern "C" void kernel_launch(void* const* d_in, const int* in_sizes, int n_in,
                              void* d_out, int out_size, void* d_ws, size_t ws_size,
                              hipStream_t stream) {
    const float* x      = (const float*)d_in[0];
    const int*   ei     = (const int*)d_in[1];
    const float* W1     = (const float*)d_in[2];
    const float* b1     = (const float*)d_in[3];
    const float* gamma1 = (const float*)d_in[4];
    const float* beta1  = (const float*)d_in[5];
    const float* W2     = (const float*)d_in[6];
    const float* b2     = (const float*)d_in[7];
    const float* gamma2 = (const float*)d_in[8];
    const float* beta2  = (const float*)d_in[9];
    const float* W3     = (const float*)d_in[10];
    const float* b3     = (const float*)d_in[11];

    int N = out_size;             // 100000 nodes
    int E = in_sizes[1] / 2;      // 6400000 edges
    const int* srcp = ei;
    const int* dstp = ei + E;

    char* w = (char*)d_ws;
    int*    csr     = (int*)w;         w += alignup((size_t)E * 4);
    int*    cnt     = (int*)w;         w += alignup((size_t)N * 4);
    int*    row_off = (int*)w;         w += alignup((size_t)(N + 1) * 4);
    int*    cursor  = (int*)w;         w += alignup((size_t)N * 4);
    float*  dinv    = (float*)w;       w += alignup((size_t)N * 4);
    uint4*  xs_h    = (uint4*)w;       w += alignup((size_t)N * 16);
    __half* h2h     = (__half*)w;      w += alignup((size_t)N * 32 * 2);
    float*  buf     = (float*)w;       w += alignup((size_t)N * 32 * 4);
    float*  pbuf    = (float*)w;       w += alignup((size_t)N * 4);
    float*  stats   = (float*)w;       w += alignup(256 * 4);
    int*    partials= (int*)w;         w += alignup(1024 * 4);

    float* sum1 = stats, *sq1 = stats + 32, *sum2 = stats + 64, *sq2 = stats + 96;
    float* a1 = stats + 128, *d1 = stats + 160, *a2 = stats + 192, *d2 = stats + 224;

    hipMemsetAsync(cnt, 0, (size_t)N * 4, stream);
    hipMemsetAsync(stats, 0, 128 * 4, stream);

    int NB = (N + 1023) / 1024;

    k_count_p<<<2048, 256, 0, stream>>>(dstp, cnt, E, N);
    k_dinv<<<(N + 255) / 256, 256, 0, stream>>>(cnt, dinv, N);
    k_xs<<<(N + 255) / 256, 256, 0, stream>>>(x, dinv, xs_h, N);
    k_scan_a<<<NB, 256, 0, stream>>>(cnt, partials, N);
    k_scan_b<<<1, 64, 0, stream>>>(partials, row_off, NB, N);
    k_scan_c<<<NB, 256, 0, stream>>>(cnt, partials, row_off, cursor, N);
    k_fill_p<<<2048, 256, 0, stream>>>(srcp, dstp, cursor, csr, E, N);

    float invN = 1.0f / (float)N;

    k_agg1<<<2048, 256, 0, stream>>>(xs_h, csr, row_off, dinv, W1, b1, buf, sum1, sq1, N);
    k_bnparam<<<1, 32, 0, stream>>>(sum1, sq1, gamma1, beta1, a1, d1, invN);
    k_h2<<<(N + 7) / 8, 256, 0, stream>>>(buf, W2, a1, d1, dinv, h2h, N);
    k_agg2<<<2048, 256, 0, stream>>>((const uint4*)h2h, csr, row_off, dinv, b2, buf, sum2, sq2, N);
    k_bnparam<<<1, 32, 0, stream>>>(sum2, sq2, gamma2, beta2, a2, d2, invN);
    k_h3p<<<(N + 7) / 8, 256, 0, stream>>>(buf, a2, d2, W3, dinv, pbuf, N);
    k_agg3<<<2048, 256, 0, stream>>>(pbuf, csr, row_off, dinv, b3, (float*)d_out, N);
}